// Round 2
// baseline (1690.330 us; speedup 1.0000x reference)
//
#include <hip/hip_runtime.h>
#include <hip/hip_bf16.h>

#define NB 2
#define SS 1024
#define EE 512
#define HH 8
#define DD 64
#define LL 4
#define FFD 2048
#define VO 17
#define MM (NB*SS)
#define CH 64
#define NCH (SS/CH)   /* 16 chunks per sequence */
#define NHH (NB*HH)   /* 16 (n,h) pairs */
#define PD 68         /* padded LDS stride */

// ---------------- embeddings + shift-right + key mask ----------------
__global__ __launch_bounds__(256) void embed_kernel(
    const int* __restrict__ seq, const int* __restrict__ dep,
    const int* __restrict__ pos, const float* __restrict__ tok,
    const float* __restrict__ dem, const float* __restrict__ sp,
    const float* __restrict__ sos, float* __restrict__ x, float* __restrict__ mask)
{
    int m = blockIdx.x;
    int s = m % SS;
    int t = threadIdx.x;
    if (t == 0) mask[m] = (seq[m] != 0) ? 1.0f : 0.0f;
    if (s == 0) {
        for (int e = t; e < EE; e += 256) x[(size_t)m*EE+e] = sos[e];
    } else {
        int mp = m - 1;
        int tk = seq[mp];
        int dh = dep[mp];
        int p0 = pos[0*NB*SS+mp], p1 = pos[1*NB*SS+mp], p2 = pos[2*NB*SS+mp];
        const float* r0 = tok + (size_t)tk*EE;
        const float* r1 = dem + (size_t)dh*EE;
        const float* r2 = sp + ((size_t)0*65 + p0)*EE;
        const float* r3 = sp + ((size_t)1*65 + p1)*EE;
        const float* r4 = sp + ((size_t)2*65 + p2)*EE;
        for (int e = t; e < EE; e += 256)
            x[(size_t)m*EE+e] = r0[e] + r1[e] + r2[e] + r3[e] + r4[e];
    }
}

// ---------------- generic fp32 GEMM: C = act(A @ W^T + bias) (+resid) ----------------
// A: [M,K] row-major, W: [Nn,K] row-major, C/resid: [M,Nn]
template<int ACT>
__global__ __launch_bounds__(256) void gemm_bt(
    const float* __restrict__ A, const float* __restrict__ W,
    const float* __restrict__ bias, const float* __restrict__ resid,
    float* __restrict__ C, int M, int Nn, int K)
{
    __shared__ float sA[16][64];
    __shared__ float sB[16][64];
    int t = threadIdx.x;
    int tx = t & 15, ty = t >> 4;
    int m0 = blockIdx.y * 64, n0 = blockIdx.x * 64;
    int lr = t >> 2;            // 0..63 tile row
    int lc = (t & 3) << 2;      // 0,4,8,12 k offset
    const float* Ap = A + (size_t)(m0+lr)*K + lc;
    const float* Wp = (n0+lr < Nn) ? (W + (size_t)(n0+lr)*K + lc) : nullptr;
    float acc[4][4] = {};
    for (int kk = 0; kk < K; kk += 16) {
        float4 a4 = *(const float4*)(Ap + kk);
        float4 b4 = Wp ? *(const float4*)(Wp + kk) : make_float4(0.f,0.f,0.f,0.f);
        __syncthreads();
        sA[lc+0][lr]=a4.x; sA[lc+1][lr]=a4.y; sA[lc+2][lr]=a4.z; sA[lc+3][lr]=a4.w;
        sB[lc+0][lr]=b4.x; sB[lc+1][lr]=b4.y; sB[lc+2][lr]=b4.z; sB[lc+3][lr]=b4.w;
        __syncthreads();
        #pragma unroll
        for (int k = 0; k < 16; ++k) {
            float4 av = *(const float4*)&sA[k][ty<<2];
            float4 bv = *(const float4*)&sB[k][tx<<2];
            float aa[4] = {av.x, av.y, av.z, av.w};
            float bb[4] = {bv.x, bv.y, bv.z, bv.w};
            #pragma unroll
            for (int i=0;i<4;++i)
                #pragma unroll
                for (int j=0;j<4;++j)
                    acc[i][j] = fmaf(aa[i], bb[j], acc[i][j]);
        }
    }
    #pragma unroll
    for (int i=0;i<4;++i) {
        int mr = m0 + (ty<<2) + i;
        #pragma unroll
        for (int j=0;j<4;++j) {
            int nc = n0 + (tx<<2) + j;
            if (nc < Nn) {
                float v = acc[i][j];
                if (bias) v += bias[nc];
                if (ACT == 1) v = 0.5f * v * (1.0f + erff(v * 0.70710678118654752f));
                if (resid) v += resid[(size_t)mr*Nn + nc];
                C[(size_t)mr*Nn + nc] = v;
            }
        }
    }
}

// ---------------- chunked linear attention, phase A: per-chunk KV = Kf^T V, zsum ----------------
__global__ __launch_bounds__(256) void attn_kv(
    const float* __restrict__ kbuf, const float* __restrict__ vbuf,
    const float* __restrict__ mask, float* __restrict__ kvc, float* __restrict__ zsum)
{
    int c = blockIdx.x, nh = blockIdx.y;
    int n = nh >> 3, h = nh & 7;
    __shared__ float sK[64][PD];
    __shared__ float sV[64][PD];
    int t = threadIdx.x;
    for (int idx = t; idx < 4096; idx += 256) {
        int i = idx >> 6, d = idx & 63;
        int m = n*SS + c*64 + i;
        float kk = kbuf[(size_t)m*EE + h*DD + d];
        float f = kk > 0.f ? kk + 1.f : expf(kk);
        sK[i][d] = f * mask[m];
        sV[i][d] = vbuf[(size_t)m*EE + h*DD + d];
    }
    __syncthreads();
    int tr = t >> 4, tc = t & 15;
    float acc[4][4] = {};
    for (int i = 0; i < 64; ++i) {
        float4 kd = *(const float4*)&sK[i][tr<<2];
        float4 vm = *(const float4*)&sV[i][tc<<2];
        float ka[4]={kd.x,kd.y,kd.z,kd.w}, vv[4]={vm.x,vm.y,vm.z,vm.w};
        #pragma unroll
        for (int a=0;a<4;++a)
            #pragma unroll
            for (int b=0;b<4;++b)
                acc[a][b] = fmaf(ka[a], vv[b], acc[a][b]);
    }
    size_t base = ((size_t)nh*NCH + c) * 4096;
    #pragma unroll
    for (int a=0;a<4;++a)
        *(float4*)&kvc[base + (size_t)((tr<<2)+a)*64 + (tc<<2)] =
            make_float4(acc[a][0],acc[a][1],acc[a][2],acc[a][3]);
    if (t < 64) {
        float z = 0.f;
        for (int i = 0; i < 64; ++i) z += sK[i][t];
        zsum[((size_t)nh*NCH + c)*64 + t] = z;
    }
}

// ---------------- phase B: exclusive prefix over chunks (state + z) ----------------
__global__ __launch_bounds__(256) void attn_prefix(
    const float* __restrict__ kvc, const float* __restrict__ zsum,
    float* __restrict__ stc, float* __restrict__ zpref)
{
    int nh = blockIdx.x;
    int t = threadIdx.x;
    size_t base = (size_t)nh * NCH * 4096;
    for (int idx = t; idx < 4096; idx += 256) {
        float run = 0.f;
        for (int c = 0; c < NCH; ++c) {
            size_t o = base + (size_t)c*4096 + idx;
            stc[o] = run;
            run += kvc[o];
        }
    }
    if (t < 64) {
        float run = 0.f;
        size_t zb = (size_t)nh * NCH * 64;
        for (int c = 0; c < NCH; ++c) {
            zpref[zb + (size_t)c*64 + t] = run;
            run += zsum[zb + (size_t)c*64 + t];
        }
    }
}

// ---------------- phase C: intra-chunk causal + inter-chunk state, normalize ----------------
__global__ __launch_bounds__(256) void attn_out(
    const float* __restrict__ qbuf, const float* __restrict__ kbuf,
    const float* __restrict__ vbuf, const float* __restrict__ mask,
    const float* __restrict__ stc, const float* __restrict__ zpref,
    float* __restrict__ att)
{
    int c = blockIdx.x, nh = blockIdx.y;
    int n = nh >> 3, h = nh & 7;
    __shared__ float sQ[64][PD], sK[64][PD], sV[64][PD], sP[64][PD];
    __shared__ float sZ[64], sInv[64];
    int t = threadIdx.x;
    for (int idx = t; idx < 4096; idx += 256) {
        int i = idx >> 6, d = idx & 63;
        int m = n*SS + c*64 + i;
        float qq = qbuf[(size_t)m*EE + h*DD + d];
        sQ[i][d] = qq > 0.f ? qq + 1.f : expf(qq);
        float kk = kbuf[(size_t)m*EE + h*DD + d];
        float f = kk > 0.f ? kk + 1.f : expf(kk);
        sK[i][d] = f * mask[m];
        sV[i][d] = vbuf[(size_t)m*EE + h*DD + d];
    }
    if (t < 64) sZ[t] = zpref[((size_t)nh*NCH + c)*64 + t];
    __syncthreads();
    int tr = t >> 4, tc = t & 15;
    // P = Qf @ Kf^T  (pre-mask)
    {
        float acc[4][4] = {};
        for (int d = 0; d < 64; d += 4) {
            float4 qa[4], kb4[4];
            #pragma unroll
            for (int a=0;a<4;++a) qa[a] = *(const float4*)&sQ[(tr<<2)+a][d];
            #pragma unroll
            for (int b=0;b<4;++b) kb4[b] = *(const float4*)&sK[(tc<<2)+b][d];
            #pragma unroll
            for (int a=0;a<4;++a) {
                float qv[4] = {qa[a].x,qa[a].y,qa[a].z,qa[a].w};
                #pragma unroll
                for (int b=0;b<4;++b) {
                    acc[a][b] += qv[0]*kb4[b].x + qv[1]*kb4[b].y
                               + qv[2]*kb4[b].z + qv[3]*kb4[b].w;
                }
            }
        }
        #pragma unroll
        for (int a=0;a<4;++a)
            *(float4*)&sP[(tr<<2)+a][tc<<2] =
                make_float4(acc[a][0],acc[a][1],acc[a][2],acc[a][3]);
    }
    __syncthreads();
    // stage inter-chunk state into sK (sK no longer needed)
    {
        size_t sb = ((size_t)nh*NCH + c) * 4096;
        for (int idx = t; idx < 4096; idx += 256)
            sK[idx>>6][idx&63] = stc[sb + idx];
    }
    // denominator per row
    if (t < 64) {
        float den = 1e-6f;
        for (int j = 0; j <= t; ++j) den += sP[t][j];
        float dz = 0.f;
        for (int d = 0; d < 64; ++d) dz += sQ[t][d] * sZ[d];
        sInv[t] = 1.0f / (den + dz);
    }
    // intra-chunk causal: sum_{j<=i} P[i][j] * V[j][:]
    float acc1[4][4] = {};
    for (int j = 0; j < 64; ++j) {
        float4 vb4 = *(const float4*)&sV[j][tc<<2];
        float vv[4] = {vb4.x, vb4.y, vb4.z, vb4.w};
        #pragma unroll
        for (int a=0;a<4;++a) {
            int i = (tr<<2)+a;
            float p = (j <= i) ? sP[i][j] : 0.f;
            #pragma unroll
            for (int b=0;b<4;++b) acc1[a][b] = fmaf(p, vv[b], acc1[a][b]);
        }
    }
    __syncthreads();   // staged state + sInv ready
    // inter-chunk: Qf @ State
    for (int d = 0; d < 64; ++d) {
        float4 sv4 = *(const float4*)&sK[d][tc<<2];
        float sv[4] = {sv4.x, sv4.y, sv4.z, sv4.w};
        #pragma unroll
        for (int a=0;a<4;++a) {
            float qv = sQ[(tr<<2)+a][d];
            #pragma unroll
            for (int b=0;b<4;++b) acc1[a][b] = fmaf(qv, sv[b], acc1[a][b]);
        }
    }
    #pragma unroll
    for (int a=0;a<4;++a) {
        int i = (tr<<2)+a;
        int m = n*SS + c*64 + i;
        float inv = sInv[i];
        *(float4*)&att[(size_t)m*EE + h*DD + (tc<<2)] =
            make_float4(acc1[a][0]*inv, acc1[a][1]*inv, acc1[a][2]*inv, acc1[a][3]*inv);
    }
}

// ---------------- LayerNorm over E=512, one block per row ----------------
__global__ __launch_bounds__(256) void ln_kernel(
    const float* __restrict__ in, const float* __restrict__ g,
    const float* __restrict__ b, float* __restrict__ out)
{
    int m = blockIdx.x;
    int t = threadIdx.x;
    float v0 = in[(size_t)m*EE + t];
    float v1 = in[(size_t)m*EE + t + 256];
    float s = v0 + v1, sq = v0*v0 + v1*v1;
    for (int o = 32; o; o >>= 1) { s += __shfl_down(s, o); sq += __shfl_down(sq, o); }
    __shared__ float ws_[4], wq_[4];
    int w = t >> 6;
    if ((t & 63) == 0) { ws_[w] = s; wq_[w] = sq; }
    __syncthreads();
    if (t == 0) {
        float S=0.f, Q=0.f;
        for (int i=0;i<4;++i){S+=ws_[i];Q+=wq_[i];}
        float mean = S * (1.0f/512.0f);
        float var = Q * (1.0f/512.0f) - mean*mean;
        ws_[0] = mean; wq_[0] = rsqrtf(var + 1e-5f);
    }
    __syncthreads();
    float mean = ws_[0], inv = wq_[0];
    out[(size_t)m*EE + t]       = (v0-mean)*inv*g[t]+b[t];
    out[(size_t)m*EE + t + 256] = (v1-mean)*inv*g[t+256]+b[t+256];
}

extern "C" void kernel_launch(void* const* d_in, const int* in_sizes, int n_in,
                              void* d_out, int out_size, void* d_ws, size_t ws_size,
                              hipStream_t stream)
{
    (void)in_sizes; (void)n_in; (void)out_size; (void)ws_size;
    const int*   seq = (const int*)d_in[0];
    const int*   dep = (const int*)d_in[1];
    const int*   pos = (const int*)d_in[2];
    const float* tok = (const float*)d_in[3];
    const float* dem = (const float*)d_in[4];
    const float* sp  = (const float*)d_in[5];
    const float* sos = (const float*)d_in[6];
    const float* Wq  = (const float*)d_in[7];
    const float* bq  = (const float*)d_in[8];
    const float* Wk  = (const float*)d_in[9];
    const float* bk  = (const float*)d_in[10];
    const float* Wv  = (const float*)d_in[11];
    const float* bv  = (const float*)d_in[12];
    const float* Wo  = (const float*)d_in[13];
    const float* bo  = (const float*)d_in[14];
    const float* g1  = (const float*)d_in[15];
    const float* b1  = (const float*)d_in[16];
    const float* W1  = (const float*)d_in[17];
    const float* bf1 = (const float*)d_in[18];
    const float* W2  = (const float*)d_in[19];
    const float* bf2 = (const float*)d_in[20];
    const float* g2  = (const float*)d_in[21];
    const float* b2  = (const float*)d_in[22];
    const float* gf  = (const float*)d_in[23];
    const float* bfn = (const float*)d_in[24];
    const float* Wh  = (const float*)d_in[25];
    float* out = (float*)d_out;

    float* ws = (float*)d_ws;
    float* x     = ws;
    float* qb    = x    + (size_t)MM*EE;
    float* kb    = qb   + (size_t)MM*EE;
    float* vb    = kb   + (size_t)MM*EE;
    float* attb  = vb   + (size_t)MM*EE;
    float* yb    = attb + (size_t)MM*EE;
    float* h1    = yb   + (size_t)MM*EE;
    float* maskb = h1   + (size_t)MM*FFD;
    float* kvc   = maskb + MM;
    float* stc   = kvc  + (size_t)NHH*NCH*DD*DD;
    float* zsum  = stc  + (size_t)NHH*NCH*DD*DD;
    float* zpref = zsum + (size_t)NHH*NCH*DD;

    dim3 blk(256);
    dim3 gE(EE/64,  MM/64);   // 8,32
    dim3 gF(FFD/64, MM/64);   // 32,32
    dim3 gH(1,      MM/64);
    dim3 gA(NCH, NHH);

    embed_kernel<<<MM, blk, 0, stream>>>(seq, dep, pos, tok, dem, sp, sos, x, maskb);
    for (int l = 0; l < LL; ++l) {
        const float* Wq_l = Wq + (size_t)l*EE*EE;
        const float* Wk_l = Wk + (size_t)l*EE*EE;
        const float* Wv_l = Wv + (size_t)l*EE*EE;
        const float* Wo_l = Wo + (size_t)l*EE*EE;
        const float* W1_l = W1 + (size_t)l*FFD*EE;
        const float* W2_l = W2 + (size_t)l*EE*FFD;
        gemm_bt<0><<<gE, blk, 0, stream>>>(x, Wq_l, bq + (size_t)l*EE, nullptr, qb, MM, EE, EE);
        gemm_bt<0><<<gE, blk, 0, stream>>>(x, Wk_l, bk + (size_t)l*EE, nullptr, kb, MM, EE, EE);
        gemm_bt<0><<<gE, blk, 0, stream>>>(x, Wv_l, bv + (size_t)l*EE, nullptr, vb, MM, EE, EE);
        attn_kv<<<gA, blk, 0, stream>>>(kb, vb, maskb, kvc, zsum);
        attn_prefix<<<NHH, blk, 0, stream>>>(kvc, zsum, stc, zpref);
        attn_out<<<gA, blk, 0, stream>>>(qb, kb, vb, maskb, stc, zpref, attb);
        gemm_bt<0><<<gE, blk, 0, stream>>>(attb, Wo_l, bo + (size_t)l*EE, x, yb, MM, EE, EE);
        ln_kernel<<<MM, blk, 0, stream>>>(yb, g1 + (size_t)l*EE, b1 + (size_t)l*EE, x);
        gemm_bt<1><<<gF, blk, 0, stream>>>(x, W1_l, bf1 + (size_t)l*FFD, nullptr, h1, MM, FFD, EE);
        gemm_bt<0><<<gE, blk, 0, stream>>>(h1, W2_l, bf2 + (size_t)l*EE, x, yb, MM, EE, FFD);
        ln_kernel<<<MM, blk, 0, stream>>>(yb, g2 + (size_t)l*EE, b2 + (size_t)l*EE, x);
    }
    ln_kernel<<<MM, blk, 0, stream>>>(x, gf, bfn, yb);
    gemm_bt<0><<<gH, blk, 0, stream>>>(yb, Wh, nullptr, nullptr, out, MM, VO, EE);
}

// Round 4
// 933.402 us; speedup vs baseline: 1.8109x; 1.8109x over previous
//
#include <hip/hip_runtime.h>
#include <hip/hip_bf16.h>

#define NB 2
#define SS 1024
#define EE 512
#define HH 8
#define DD 64
#define LL 4
#define FFD 2048
#define VO 17
#define MM (NB*SS)
#define CH 64
#define NCH (SS/CH)   /* 16 chunks per sequence */
#define NHH (NB*HH)   /* 16 (n,h) pairs */
#define PD 68         /* padded LDS stride */

typedef __attribute__((ext_vector_type(8))) short bshort8;
typedef __attribute__((ext_vector_type(4))) float f32x4;

__device__ __forceinline__ unsigned short f2b(float f) {
    unsigned int u = __float_as_uint(f);
    u += 0x7fffu + ((u >> 16) & 1u);          // RNE to bf16 (finite inputs)
    return (unsigned short)(u >> 16);
}
__device__ __forceinline__ bshort8 pack8(float4 a, float4 b) {
    bshort8 r;
    r[0]=(short)f2b(a.x); r[1]=(short)f2b(a.y); r[2]=(short)f2b(a.z); r[3]=(short)f2b(a.w);
    r[4]=(short)f2b(b.x); r[5]=(short)f2b(b.y); r[6]=(short)f2b(b.z); r[7]=(short)f2b(b.w);
    return r;
}

// ---------------- embeddings + shift-right + key mask ----------------
__global__ __launch_bounds__(256) void embed_kernel(
    const int* __restrict__ seq, const int* __restrict__ dep,
    const int* __restrict__ pos, const float* __restrict__ tok,
    const float* __restrict__ dem, const float* __restrict__ sp,
    const float* __restrict__ sos, float* __restrict__ x, float* __restrict__ mask)
{
    int m = blockIdx.x;
    int s = m % SS;
    int t = threadIdx.x;
    if (t == 0) mask[m] = (seq[m] != 0) ? 1.0f : 0.0f;
    if (s == 0) {
        for (int e = t; e < EE; e += 256) x[(size_t)m*EE+e] = sos[e];
    } else {
        int mp = m - 1;
        int tk = seq[mp];
        int dh = dep[mp];
        int p0 = pos[0*NB*SS+mp], p1 = pos[1*NB*SS+mp], p2 = pos[2*NB*SS+mp];
        const float* r0 = tok + (size_t)tk*EE;
        const float* r1 = dem + (size_t)dh*EE;
        const float* r2 = sp + ((size_t)0*65 + p0)*EE;
        const float* r3 = sp + ((size_t)1*65 + p1)*EE;
        const float* r4 = sp + ((size_t)2*65 + p2)*EE;
        for (int e = t; e < EE; e += 256)
            x[(size_t)m*EE+e] = r0[e] + r1[e] + r2[e] + r3[e] + r4[e];
    }
}

// ---------------- bf16 MFMA GEMM: C = act(A @ W^T + bias) (+fp32 resid) ----------------
// A: [M,K] fp32 row-major, W: [Nn,K] fp32 row-major (converted to bf16 at staging).
// 64x64 tile, BK=64, 4 waves each computing a 32x32 sub-tile via 16x16x32 MFMA.
// M, Nn, K must be multiples of 64.
template<int ACT>
__global__ __launch_bounds__(256) void gemm_mfma(
    const float* __restrict__ A, const float* __restrict__ W,
    const float* __restrict__ bias, const float* __restrict__ resid,
    float* __restrict__ C, int M, int Nn, int K)
{
    __shared__ unsigned short sA[64][72];   // +8 pad: row stride 144B, ~2-way banks
    __shared__ unsigned short sB[64][72];
    int t = threadIdx.x;
    int m0 = blockIdx.y * 64, n0 = blockIdx.x * 64;
    int lane = t & 63, w = t >> 6;
    int wr = w >> 1, wc = w & 1;
    int srow = t >> 2, sk = (t & 3) << 4;   // 4 threads/row, 16 fp32 each
    const float* Ap = A + (size_t)(m0+srow)*K + sk;
    const float* Wp = W + (size_t)(n0+srow)*K + sk;
    int l15 = lane & 15, lk = (lane >> 4) << 3;
    f32x4 acc[2][2] = {};
    for (int kk = 0; kk < K; kk += 64) {
        float4 a0 = *(const float4*)(Ap+kk);
        float4 a1 = *(const float4*)(Ap+kk+4);
        float4 a2 = *(const float4*)(Ap+kk+8);
        float4 a3 = *(const float4*)(Ap+kk+12);
        float4 b0 = *(const float4*)(Wp+kk);
        float4 b1 = *(const float4*)(Wp+kk+4);
        float4 b2 = *(const float4*)(Wp+kk+8);
        float4 b3 = *(const float4*)(Wp+kk+12);
        __syncthreads();
        *(bshort8*)&sA[srow][sk]   = pack8(a0,a1);
        *(bshort8*)&sA[srow][sk+8] = pack8(a2,a3);
        *(bshort8*)&sB[srow][sk]   = pack8(b0,b1);
        *(bshort8*)&sB[srow][sk+8] = pack8(b2,b3);
        __syncthreads();
        #pragma unroll
        for (int ks = 0; ks < 2; ++ks) {
            bshort8 af[2], bf[2];
            #pragma unroll
            for (int mi=0;mi<2;++mi)
                af[mi] = *(const bshort8*)&sA[wr*32+mi*16+l15][ks*32+lk];
            #pragma unroll
            for (int ni=0;ni<2;++ni)
                bf[ni] = *(const bshort8*)&sB[wc*32+ni*16+l15][ks*32+lk];
            #pragma unroll
            for (int mi=0;mi<2;++mi)
                #pragma unroll
                for (int ni=0;ni<2;++ni)
                    acc[mi][ni] = __builtin_amdgcn_mfma_f32_16x16x32_bf16(
                        af[mi], bf[ni], acc[mi][ni], 0, 0, 0);
        }
    }
    int r0 = (lane >> 4) << 2;
    #pragma unroll
    for (int mi=0;mi<2;++mi) {
        #pragma unroll
        for (int ni=0;ni<2;++ni) {
            int col = n0 + wc*32 + ni*16 + l15;
            float bs = bias ? bias[col] : 0.f;
            #pragma unroll
            for (int r=0;r<4;++r) {
                int row = m0 + wr*32 + mi*16 + r0 + r;
                float v = acc[mi][ni][r] + bs;
                if (ACT == 1) v = 0.5f * v * (1.0f + erff(v * 0.70710678118654752f));
                if (resid) v += resid[(size_t)row*Nn + col];
                C[(size_t)row*Nn + col] = v;
            }
        }
    }
}

// ---------------- fp32 GEMM (head only, Nn=17): C = A @ W^T ----------------
template<int ACT>
__global__ __launch_bounds__(256) void gemm_bt(
    const float* __restrict__ A, const float* __restrict__ W,
    const float* __restrict__ bias, const float* __restrict__ resid,
    float* __restrict__ C, int M, int Nn, int K)
{
    __shared__ float sA[16][64];
    __shared__ float sB[16][64];
    int t = threadIdx.x;
    int tx = t & 15, ty = t >> 4;
    int m0 = blockIdx.y * 64, n0 = blockIdx.x * 64;
    int lr = t >> 2;
    int lc = (t & 3) << 2;
    const float* Ap = A + (size_t)(m0+lr)*K + lc;
    const float* Wp = (n0+lr < Nn) ? (W + (size_t)(n0+lr)*K + lc) : nullptr;
    float acc[4][4] = {};
    for (int kk = 0; kk < K; kk += 16) {
        float4 a4 = *(const float4*)(Ap + kk);
        float4 b4 = Wp ? *(const float4*)(Wp + kk) : make_float4(0.f,0.f,0.f,0.f);
        __syncthreads();
        sA[lc+0][lr]=a4.x; sA[lc+1][lr]=a4.y; sA[lc+2][lr]=a4.z; sA[lc+3][lr]=a4.w;
        sB[lc+0][lr]=b4.x; sB[lc+1][lr]=b4.y; sB[lc+2][lr]=b4.z; sB[lc+3][lr]=b4.w;
        __syncthreads();
        #pragma unroll
        for (int k = 0; k < 16; ++k) {
            float4 av = *(const float4*)&sA[k][ty<<2];
            float4 bv = *(const float4*)&sB[k][tx<<2];
            float aa[4] = {av.x, av.y, av.z, av.w};
            float bb[4] = {bv.x, bv.y, bv.z, bv.w};
            #pragma unroll
            for (int i=0;i<4;++i)
                #pragma unroll
                for (int j=0;j<4;++j)
                    acc[i][j] = fmaf(aa[i], bb[j], acc[i][j]);
        }
    }
    #pragma unroll
    for (int i=0;i<4;++i) {
        int mr = m0 + (ty<<2) + i;
        #pragma unroll
        for (int j=0;j<4;++j) {
            int nc = n0 + (tx<<2) + j;
            if (nc < Nn) {
                float v = acc[i][j];
                if (bias) v += bias[nc];
                if (ACT == 1) v = 0.5f * v * (1.0f + erff(v * 0.70710678118654752f));
                if (resid) v += resid[(size_t)mr*Nn + nc];
                C[(size_t)mr*Nn + nc] = v;
            }
        }
    }
}

// ---------------- chunked linear attention, phase A: per-chunk KV = Kf^T V, zsum ----------------
__global__ __launch_bounds__(256) void attn_kv(
    const float* __restrict__ kbuf, const float* __restrict__ vbuf,
    const float* __restrict__ mask, float* __restrict__ kvc, float* __restrict__ zsum)
{
    int c = blockIdx.x, nh = blockIdx.y;
    int n = nh >> 3, h = nh & 7;
    __shared__ float sK[64][PD];
    __shared__ float sV[64][PD];
    int t = threadIdx.x;
    for (int idx = t; idx < 4096; idx += 256) {
        int i = idx >> 6, d = idx & 63;
        int m = n*SS + c*64 + i;
        float kk = kbuf[(size_t)m*EE + h*DD + d];
        float f = kk > 0.f ? kk + 1.f : expf(kk);
        sK[i][d] = f * mask[m];
        sV[i][d] = vbuf[(size_t)m*EE + h*DD + d];
    }
    __syncthreads();
    int tr = t >> 4, tc = t & 15;
    float acc[4][4] = {};
    for (int i = 0; i < 64; ++i) {
        float4 kd = *(const float4*)&sK[i][tr<<2];
        float4 vm = *(const float4*)&sV[i][tc<<2];
        float ka[4]={kd.x,kd.y,kd.z,kd.w}, vv[4]={vm.x,vm.y,vm.z,vm.w};
        #pragma unroll
        for (int a=0;a<4;++a)
            #pragma unroll
            for (int b=0;b<4;++b)
                acc[a][b] = fmaf(ka[a], vv[b], acc[a][b]);
    }
    size_t base = ((size_t)nh*NCH + c) * 4096;
    #pragma unroll
    for (int a=0;a<4;++a)
        *(float4*)&kvc[base + (size_t)((tr<<2)+a)*64 + (tc<<2)] =
            make_float4(acc[a][0],acc[a][1],acc[a][2],acc[a][3]);
    if (t < 64) {
        float z = 0.f;
        for (int i = 0; i < 64; ++i) z += sK[i][t];
        zsum[((size_t)nh*NCH + c)*64 + t] = z;
    }
}

// ---------------- phase B: exclusive prefix over chunks (state + z) ----------------
__global__ __launch_bounds__(256) void attn_prefix(
    const float* __restrict__ kvc, const float* __restrict__ zsum,
    float* __restrict__ stc, float* __restrict__ zpref)
{
    int nh = blockIdx.x;
    int t = threadIdx.x;
    size_t base = (size_t)nh * NCH * 4096;
    for (int idx = t; idx < 4096; idx += 256) {
        float run = 0.f;
        for (int c = 0; c < NCH; ++c) {
            size_t o = base + (size_t)c*4096 + idx;
            stc[o] = run;
            run += kvc[o];
        }
    }
    if (t < 64) {
        float run = 0.f;
        size_t zb = (size_t)nh * NCH * 64;
        for (int c = 0; c < NCH; ++c) {
            zpref[zb + (size_t)c*64 + t] = run;
            run += zsum[zb + (size_t)c*64 + t];
        }
    }
}

// ---------------- phase C: intra-chunk causal + inter-chunk state, normalize ----------------
__global__ __launch_bounds__(256) void attn_out(
    const float* __restrict__ qbuf, const float* __restrict__ kbuf,
    const float* __restrict__ vbuf, const float* __restrict__ mask,
    const float* __restrict__ stc, const float* __restrict__ zpref,
    float* __restrict__ att)
{
    int c = blockIdx.x, nh = blockIdx.y;
    int n = nh >> 3, h = nh & 7;
    __shared__ float sQ[64][PD], sK[64][PD], sV[64][PD], sP[64][PD];
    __shared__ float sZ[64], sInv[64];
    int t = threadIdx.x;
    for (int idx = t; idx < 4096; idx += 256) {
        int i = idx >> 6, d = idx & 63;
        int m = n*SS + c*64 + i;
        float qq = qbuf[(size_t)m*EE + h*DD + d];
        sQ[i][d] = qq > 0.f ? qq + 1.f : expf(qq);
        float kk = kbuf[(size_t)m*EE + h*DD + d];
        float f = kk > 0.f ? kk + 1.f : expf(kk);
        sK[i][d] = f * mask[m];
        sV[i][d] = vbuf[(size_t)m*EE + h*DD + d];
    }
    if (t < 64) sZ[t] = zpref[((size_t)nh*NCH + c)*64 + t];
    __syncthreads();
    int tr = t >> 4, tc = t & 15;
    // P = Qf @ Kf^T  (pre-mask)
    {
        float acc[4][4] = {};
        for (int d = 0; d < 64; d += 4) {
            float4 qa[4], kb4[4];
            #pragma unroll
            for (int a=0;a<4;++a) qa[a] = *(const float4*)&sQ[(tr<<2)+a][d];
            #pragma unroll
            for (int b=0;b<4;++b) kb4[b] = *(const float4*)&sK[(tc<<2)+b][d];
            #pragma unroll
            for (int a=0;a<4;++a) {
                float qv[4] = {qa[a].x,qa[a].y,qa[a].z,qa[a].w};
                #pragma unroll
                for (int b=0;b<4;++b) {
                    acc[a][b] += qv[0]*kb4[b].x + qv[1]*kb4[b].y
                               + qv[2]*kb4[b].z + qv[3]*kb4[b].w;
                }
            }
        }
        #pragma unroll
        for (int a=0;a<4;++a)
            *(float4*)&sP[(tr<<2)+a][tc<<2] =
                make_float4(acc[a][0],acc[a][1],acc[a][2],acc[a][3]);
    }
    __syncthreads();
    // stage inter-chunk state into sK (sK no longer needed)
    {
        size_t sb = ((size_t)nh*NCH + c) * 4096;
        for (int idx = t; idx < 4096; idx += 256)
            sK[idx>>6][idx&63] = stc[sb + idx];
    }
    // denominator per row
    if (t < 64) {
        float den = 1e-6f;
        for (int j = 0; j <= t; ++j) den += sP[t][j];
        float dz = 0.f;
        for (int d = 0; d < 64; ++d) dz += sQ[t][d] * sZ[d];
        sInv[t] = 1.0f / (den + dz);
    }
    // intra-chunk causal: sum_{j<=i} P[i][j] * V[j][:]
    float acc1[4][4] = {};
    for (int j = 0; j < 64; ++j) {
        float4 vb4 = *(const float4*)&sV[j][tc<<2];
        float vv[4] = {vb4.x, vb4.y, vb4.z, vb4.w};
        #pragma unroll
        for (int a=0;a<4;++a) {
            int i = (tr<<2)+a;
            float p = (j <= i) ? sP[i][j] : 0.f;
            #pragma unroll
            for (int b=0;b<4;++b) acc1[a][b] = fmaf(p, vv[b], acc1[a][b]);
        }
    }
    __syncthreads();   // staged state + sInv ready
    // inter-chunk: Qf @ State
    for (int d = 0; d < 64; ++d) {
        float4 sv4 = *(const float4*)&sK[d][tc<<2];
        float sv[4] = {sv4.x, sv4.y, sv4.z, sv4.w};
        #pragma unroll
        for (int a=0;a<4;++a) {
            float qv = sQ[(tr<<2)+a][d];
            #pragma unroll
            for (int b=0;b<4;++b) acc1[a][b] = fmaf(qv, sv[b], acc1[a][b]);
        }
    }
    #pragma unroll
    for (int a=0;a<4;++a) {
        int i = (tr<<2)+a;
        int m = n*SS + c*64 + i;
        float inv = sInv[i];
        *(float4*)&att[(size_t)m*EE + h*DD + (tc<<2)] =
            make_float4(acc1[a][0]*inv, acc1[a][1]*inv, acc1[a][2]*inv, acc1[a][3]*inv);
    }
}

// ---------------- LayerNorm over E=512, one block per row ----------------
__global__ __launch_bounds__(256) void ln_kernel(
    const float* __restrict__ in, const float* __restrict__ g,
    const float* __restrict__ b, float* __restrict__ out)
{
    int m = blockIdx.x;
    int t = threadIdx.x;
    float v0 = in[(size_t)m*EE + t];
    float v1 = in[(size_t)m*EE + t + 256];
    float s = v0 + v1, sq = v0*v0 + v1*v1;
    for (int o = 32; o; o >>= 1) { s += __shfl_down(s, o); sq += __shfl_down(sq, o); }
    __shared__ float ws_[4], wq_[4];
    int w = t >> 6;
    if ((t & 63) == 0) { ws_[w] = s; wq_[w] = sq; }
    __syncthreads();
    if (t == 0) {
        float S=0.f, Q=0.f;
        for (int i=0;i<4;++i){S+=ws_[i];Q+=wq_[i];}
        float mean = S * (1.0f/512.0f);
        float var = Q * (1.0f/512.0f) - mean*mean;
        ws_[0] = mean; wq_[0] = rsqrtf(var + 1e-5f);
    }
    __syncthreads();
    float mean = ws_[0], inv = wq_[0];
    out[(size_t)m*EE + t]       = (v0-mean)*inv*g[t]+b[t];
    out[(size_t)m*EE + t + 256] = (v1-mean)*inv*g[t+256]+b[t+256];
}

extern "C" void kernel_launch(void* const* d_in, const int* in_sizes, int n_in,
                              void* d_out, int out_size, void* d_ws, size_t ws_size,
                              hipStream_t stream)
{
    (void)in_sizes; (void)n_in; (void)out_size; (void)ws_size;
    const int*   seq = (const int*)d_in[0];
    const int*   dep = (const int*)d_in[1];
    const int*   pos = (const int*)d_in[2];
    const float* tok = (const float*)d_in[3];
    const float* dem = (const float*)d_in[4];
    const float* sp  = (const float*)d_in[5];
    const float* sos = (const float*)d_in[6];
    const float* Wq  = (const float*)d_in[7];
    const float* bq  = (const float*)d_in[8];
    const float* Wk  = (const float*)d_in[9];
    const float* bk  = (const float*)d_in[10];
    const float* Wv  = (const float*)d_in[11];
    const float* bv  = (const float*)d_in[12];
    const float* Wo  = (const float*)d_in[13];
    const float* bo  = (const float*)d_in[14];
    const float* g1  = (const float*)d_in[15];
    const float* b1  = (const float*)d_in[16];
    const float* W1  = (const float*)d_in[17];
    const float* bf1 = (const float*)d_in[18];
    const float* W2  = (const float*)d_in[19];
    const float* bf2 = (const float*)d_in[20];
    const float* g2  = (const float*)d_in[21];
    const float* b2  = (const float*)d_in[22];
    const float* gf  = (const float*)d_in[23];
    const float* bfn = (const float*)d_in[24];
    const float* Wh  = (const float*)d_in[25];
    float* out = (float*)d_out;

    float* ws = (float*)d_ws;
    float* x     = ws;
    float* qb    = x    + (size_t)MM*EE;
    float* kb    = qb   + (size_t)MM*EE;
    float* vb    = kb   + (size_t)MM*EE;
    float* attb  = vb   + (size_t)MM*EE;
    float* yb    = attb + (size_t)MM*EE;
    float* h1    = yb   + (size_t)MM*EE;
    float* maskb = h1   + (size_t)MM*FFD;
    float* kvc   = maskb + MM;
    float* stc   = kvc  + (size_t)NHH*NCH*DD*DD;
    float* zsum  = stc  + (size_t)NHH*NCH*DD*DD;
    float* zpref = zsum + (size_t)NHH*NCH*DD;

    dim3 blk(256);
    dim3 gE(EE/64,  MM/64);   // 8,32
    dim3 gF(FFD/64, MM/64);   // 32,32
    dim3 gH(1,      MM/64);
    dim3 gA(NCH, NHH);

    embed_kernel<<<MM, blk, 0, stream>>>(seq, dep, pos, tok, dem, sp, sos, x, maskb);
    for (int l = 0; l < LL; ++l) {
        const float* Wq_l = Wq + (size_t)l*EE*EE;
        const float* Wk_l = Wk + (size_t)l*EE*EE;
        const float* Wv_l = Wv + (size_t)l*EE*EE;
        const float* Wo_l = Wo + (size_t)l*EE*EE;
        const float* W1_l = W1 + (size_t)l*FFD*EE;
        const float* W2_l = W2 + (size_t)l*EE*FFD;
        gemm_mfma<0><<<gE, blk, 0, stream>>>(x, Wq_l, bq + (size_t)l*EE, nullptr, qb, MM, EE, EE);
        gemm_mfma<0><<<gE, blk, 0, stream>>>(x, Wk_l, bk + (size_t)l*EE, nullptr, kb, MM, EE, EE);
        gemm_mfma<0><<<gE, blk, 0, stream>>>(x, Wv_l, bv + (size_t)l*EE, nullptr, vb, MM, EE, EE);
        attn_kv<<<gA, blk, 0, stream>>>(kb, vb, maskb, kvc, zsum);
        attn_prefix<<<NHH, blk, 0, stream>>>(kvc, zsum, stc, zpref);
        attn_out<<<gA, blk, 0, stream>>>(qb, kb, vb, maskb, stc, zpref, attb);
        gemm_mfma<0><<<gE, blk, 0, stream>>>(attb, Wo_l, bo + (size_t)l*EE, x, yb, MM, EE, EE);
        ln_kernel<<<MM, blk, 0, stream>>>(yb, g1 + (size_t)l*EE, b1 + (size_t)l*EE, x);
        gemm_mfma<1><<<gF, blk, 0, stream>>>(x, W1_l, bf1 + (size_t)l*FFD, nullptr, h1, MM, FFD, EE);
        gemm_mfma<0><<<gE, blk, 0, stream>>>(h1, W2_l, bf2 + (size_t)l*EE, x, yb, MM, EE, FFD);
        ln_kernel<<<MM, blk, 0, stream>>>(yb, g2 + (size_t)l*EE, b2 + (size_t)l*EE, x);
    }
    ln_kernel<<<MM, blk, 0, stream>>>(x, gf, bfn, yb);
    gemm_bt<0><<<gH, blk, 0, stream>>>(yb, Wh, nullptr, nullptr, out, MM, VO, EE);
}

// Round 5
// 599.309 us; speedup vs baseline: 2.8205x; 1.5575x over previous
//
#include <hip/hip_runtime.h>
#include <hip/hip_bf16.h>

#define NB 2
#define SS 1024
#define EE 512
#define HH 8
#define DD 64
#define LL 4
#define FFD 2048
#define VO 17
#define MM (NB*SS)
#define CH 64
#define NCH (SS/CH)   /* 16 chunks per sequence */
#define NHH (NB*HH)   /* 16 (n,h) pairs */
#define PD 68         /* padded LDS stride (fp32 attn tiles) */

typedef __attribute__((ext_vector_type(8))) short bshort8;
typedef __attribute__((ext_vector_type(4))) float f32x4;
typedef unsigned short u16;

__device__ __forceinline__ float b2f(u16 u) {
    return __uint_as_float(((unsigned)u) << 16);
}
__device__ __forceinline__ u16 f2b(float f) {
    unsigned u = __float_as_uint(f);
    u += 0x7fffu + ((u >> 16) & 1u);          // RNE to bf16 (finite inputs)
    return (u16)(u >> 16);
}

// ---------------- fp32 -> bf16 bulk convert (weights, once per launch) ----------------
__global__ __launch_bounds__(256) void f2b_kernel(
    const float* __restrict__ in, u16* __restrict__ out)
{
    int i = (blockIdx.x * 256 + threadIdx.x) * 8;
    float4 v0 = *(const float4*)(in + i);
    float4 v1 = *(const float4*)(in + i + 4);
    bshort8 r;
    r[0]=(short)f2b(v0.x); r[1]=(short)f2b(v0.y); r[2]=(short)f2b(v0.z); r[3]=(short)f2b(v0.w);
    r[4]=(short)f2b(v1.x); r[5]=(short)f2b(v1.y); r[6]=(short)f2b(v1.z); r[7]=(short)f2b(v1.w);
    *(bshort8*)(out + i) = r;
}

// ---------------- embeddings + shift-right + key mask (dual fp32/bf16 out) ----------------
__global__ __launch_bounds__(256) void embed_kernel(
    const int* __restrict__ seq, const int* __restrict__ dep,
    const int* __restrict__ pos, const float* __restrict__ tok,
    const float* __restrict__ dem, const float* __restrict__ sp,
    const float* __restrict__ sos, float* __restrict__ xf, u16* __restrict__ xh,
    float* __restrict__ mask)
{
    int m = blockIdx.x;
    int s = m % SS;
    int t = threadIdx.x;
    if (t == 0) mask[m] = (seq[m] != 0) ? 1.0f : 0.0f;
    if (s == 0) {
        for (int e = t; e < EE; e += 256) {
            float v = sos[e];
            xf[(size_t)m*EE+e] = v; xh[(size_t)m*EE+e] = f2b(v);
        }
    } else {
        int mp = m - 1;
        int tk = seq[mp];
        int dh = dep[mp];
        int p0 = pos[0*NB*SS+mp], p1 = pos[1*NB*SS+mp], p2 = pos[2*NB*SS+mp];
        const float* r0 = tok + (size_t)tk*EE;
        const float* r1 = dem + (size_t)dh*EE;
        const float* r2 = sp + ((size_t)0*65 + p0)*EE;
        const float* r3 = sp + ((size_t)1*65 + p1)*EE;
        const float* r4 = sp + ((size_t)2*65 + p2)*EE;
        for (int e = t; e < EE; e += 256) {
            float v = r0[e] + r1[e] + r2[e] + r3[e] + r4[e];
            xf[(size_t)m*EE+e] = v; xh[(size_t)m*EE+e] = f2b(v);
        }
    }
}

// ---------------- bf16 MFMA GEMM body: C = act(A @ W^T + bias) (+fp32 resid) ----------------
// A: [M,K] bf16, W: [Nn,K] bf16. 64x64 tile, BK=64 double-buffered LDS, ONE barrier
// per K-tile; next-tile global loads issued before compute (latency hidden).
// 4 waves, each a 32x32 sub-tile (2x2 frags of 16x16x32).
template<int ACT, int OUTF>
__device__ __forceinline__ void gemm_body(
    const u16* __restrict__ A, const u16* __restrict__ W,
    const float* __restrict__ bias, const float* __restrict__ residf,
    float* __restrict__ Cf, u16* __restrict__ Ch,
    int m0, int n0, int Nn, int K)
{
    __shared__ u16 sA[2][64][72];   // 144B row stride: 16B-aligned, ~2-way banks
    __shared__ u16 sB[2][64][72];
    int t = threadIdx.x;
    int lane = t & 63, w = t >> 6, wr = w >> 1, wc = w & 1;
    int l15 = lane & 15, lk = (lane >> 4) << 3;
    int sr = t >> 2, sc = (t & 3) << 4;          // 4 threads/row, 16 bf16 each
    const u16* Ap = A + (size_t)(m0 + sr) * K + sc;
    const u16* Wp = W + (size_t)(n0 + sr) * K + sc;
    int T = K >> 6;
    bshort8 ra0 = *(const bshort8*)(Ap);
    bshort8 ra1 = *(const bshort8*)(Ap + 8);
    bshort8 rb0 = *(const bshort8*)(Wp);
    bshort8 rb1 = *(const bshort8*)(Wp + 8);
    *(bshort8*)&sA[0][sr][sc]   = ra0;  *(bshort8*)&sA[0][sr][sc+8] = ra1;
    *(bshort8*)&sB[0][sr][sc]   = rb0;  *(bshort8*)&sB[0][sr][sc+8] = rb1;
    __syncthreads();
    f32x4 acc[2][2] = {};
    for (int tt = 0; tt < T; ++tt) {
        int cur = tt & 1;
        bool more = (tt + 1 < T);
        if (more) {                               // issue next-tile loads early
            int kk = (tt + 1) << 6;
            ra0 = *(const bshort8*)(Ap + kk);
            ra1 = *(const bshort8*)(Ap + kk + 8);
            rb0 = *(const bshort8*)(Wp + kk);
            rb1 = *(const bshort8*)(Wp + kk + 8);
        }
        #pragma unroll
        for (int ks = 0; ks < 2; ++ks) {
            bshort8 af[2], bfr[2];
            #pragma unroll
            for (int mi=0;mi<2;++mi)
                af[mi] = *(const bshort8*)&sA[cur][wr*32+mi*16+l15][(ks<<5)+lk];
            #pragma unroll
            for (int ni=0;ni<2;++ni)
                bfr[ni] = *(const bshort8*)&sB[cur][wc*32+ni*16+l15][(ks<<5)+lk];
            #pragma unroll
            for (int mi=0;mi<2;++mi)
                #pragma unroll
                for (int ni=0;ni<2;++ni)
                    acc[mi][ni] = __builtin_amdgcn_mfma_f32_16x16x32_bf16(
                        af[mi], bfr[ni], acc[mi][ni], 0, 0, 0);
        }
        if (more) {
            int nxt = cur ^ 1;
            *(bshort8*)&sA[nxt][sr][sc]   = ra0;  *(bshort8*)&sA[nxt][sr][sc+8] = ra1;
            *(bshort8*)&sB[nxt][sr][sc]   = rb0;  *(bshort8*)&sB[nxt][sr][sc+8] = rb1;
            __syncthreads();                      // one barrier per K-tile
        }
    }
    int r0 = (lane >> 4) << 2;
    #pragma unroll
    for (int mi=0;mi<2;++mi) {
        #pragma unroll
        for (int ni=0;ni<2;++ni) {
            int col = n0 + wc*32 + ni*16 + l15;
            float bs = bias[col];
            #pragma unroll
            for (int r=0;r<4;++r) {
                int row = m0 + wr*32 + mi*16 + r0 + r;
                float v = acc[mi][ni][r] + bs;
                if (ACT == 1) v = 0.5f * v * (1.0f + erff(v * 0.70710678118654752f));
                if (OUTF) {
                    v += residf[(size_t)row*Nn + col];
                    Cf[(size_t)row*Nn + col] = v;
                } else {
                    Ch[(size_t)row*Nn + col] = f2b(v);
                }
            }
        }
    }
}

template<int ACT, int OUTF>
__global__ __launch_bounds__(256) void gemm_k(
    const u16* __restrict__ A, const u16* __restrict__ W,
    const float* __restrict__ bias, const float* __restrict__ residf,
    float* __restrict__ Cf, u16* __restrict__ Ch, int Nn, int K)
{
    gemm_body<ACT,OUTF>(A, W, bias, residf, Cf, Ch,
                        blockIdx.y*64, blockIdx.x*64, Nn, K);
}

// fused Q,K,V: blockIdx.z selects projection -> 3x grid, 3 blocks/CU
__global__ __launch_bounds__(256) void gemm_qkv(
    const u16* __restrict__ A,
    const u16* __restrict__ Wq, const u16* __restrict__ Wk, const u16* __restrict__ Wv,
    const float* __restrict__ bq, const float* __restrict__ bk, const float* __restrict__ bv,
    u16* __restrict__ qb, u16* __restrict__ kb, u16* __restrict__ vb, int Nn, int K)
{
    int z = blockIdx.z;
    const u16* W = (z==0) ? Wq : (z==1 ? Wk : Wv);
    const float* bias = (z==0) ? bq : (z==1 ? bk : bv);
    u16* Ch = (z==0) ? qb : (z==1 ? kb : vb);
    gemm_body<0,0>(A, W, bias, nullptr, nullptr, Ch,
                   blockIdx.y*64, blockIdx.x*64, Nn, K);
}

// ---------------- fp32 GEMM (head only, Nn=17): C = A @ W^T ----------------
__global__ __launch_bounds__(256) void gemm_head(
    const float* __restrict__ A, const float* __restrict__ W,
    float* __restrict__ C, int M, int Nn, int K)
{
    __shared__ float sA[16][64];
    __shared__ float sB[16][64];
    int t = threadIdx.x;
    int tx = t & 15, ty = t >> 4;
    int m0 = blockIdx.y * 64, n0 = blockIdx.x * 64;
    int lr = t >> 2;
    int lc = (t & 3) << 2;
    const float* Ap = A + (size_t)(m0+lr)*K + lc;
    const float* Wp = (n0+lr < Nn) ? (W + (size_t)(n0+lr)*K + lc) : nullptr;
    float acc[4][4] = {};
    for (int kk = 0; kk < K; kk += 16) {
        float4 a4 = *(const float4*)(Ap + kk);
        float4 b4 = Wp ? *(const float4*)(Wp + kk) : make_float4(0.f,0.f,0.f,0.f);
        __syncthreads();
        sA[lc+0][lr]=a4.x; sA[lc+1][lr]=a4.y; sA[lc+2][lr]=a4.z; sA[lc+3][lr]=a4.w;
        sB[lc+0][lr]=b4.x; sB[lc+1][lr]=b4.y; sB[lc+2][lr]=b4.z; sB[lc+3][lr]=b4.w;
        __syncthreads();
        #pragma unroll
        for (int k = 0; k < 16; ++k) {
            float4 av = *(const float4*)&sA[k][ty<<2];
            float4 bv = *(const float4*)&sB[k][tx<<2];
            float aa[4] = {av.x, av.y, av.z, av.w};
            float bb[4] = {bv.x, bv.y, bv.z, bv.w};
            #pragma unroll
            for (int i=0;i<4;++i)
                #pragma unroll
                for (int j=0;j<4;++j)
                    acc[i][j] = fmaf(aa[i], bb[j], acc[i][j]);
        }
    }
    #pragma unroll
    for (int i=0;i<4;++i) {
        int mr = m0 + (ty<<2) + i;
        #pragma unroll
        for (int j=0;j<4;++j) {
            int nc = n0 + (tx<<2) + j;
            if (nc < Nn) C[(size_t)mr*Nn + nc] = acc[i][j];
        }
    }
}

// ---------------- chunked linear attention, phase A: per-chunk KV = Kf^T V, zsum ----------------
__global__ __launch_bounds__(256) void attn_kv(
    const u16* __restrict__ kbuf, const u16* __restrict__ vbuf,
    const float* __restrict__ mask, float* __restrict__ kvc, float* __restrict__ zsum)
{
    int c = blockIdx.x, nh = blockIdx.y;
    int n = nh >> 3, h = nh & 7;
    __shared__ float sK[64][PD];
    __shared__ float sV[64][PD];
    int t = threadIdx.x;
    for (int idx = t; idx < 4096; idx += 256) {
        int i = idx >> 6, d = idx & 63;
        int m = n*SS + c*64 + i;
        float kk = b2f(kbuf[(size_t)m*EE + h*DD + d]);
        float f = kk > 0.f ? kk + 1.f : expf(kk);
        sK[i][d] = f * mask[m];
        sV[i][d] = b2f(vbuf[(size_t)m*EE + h*DD + d]);
    }
    __syncthreads();
    int tr = t >> 4, tc = t & 15;
    float acc[4][4] = {};
    for (int i = 0; i < 64; ++i) {
        float4 kd = *(const float4*)&sK[i][tr<<2];
        float4 vm = *(const float4*)&sV[i][tc<<2];
        float ka[4]={kd.x,kd.y,kd.z,kd.w}, vv[4]={vm.x,vm.y,vm.z,vm.w};
        #pragma unroll
        for (int a=0;a<4;++a)
            #pragma unroll
            for (int b=0;b<4;++b)
                acc[a][b] = fmaf(ka[a], vv[b], acc[a][b]);
    }
    size_t base = ((size_t)nh*NCH + c) * 4096;
    #pragma unroll
    for (int a=0;a<4;++a)
        *(float4*)&kvc[base + (size_t)((tr<<2)+a)*64 + (tc<<2)] =
            make_float4(acc[a][0],acc[a][1],acc[a][2],acc[a][3]);
    if (t < 64) {
        float z = 0.f;
        for (int i = 0; i < 64; ++i) z += sK[i][t];
        zsum[((size_t)nh*NCH + c)*64 + t] = z;
    }
}

// ---------------- phase B: IN-PLACE exclusive prefix over chunks (state + z) ----------------
__global__ __launch_bounds__(256) void attn_prefix(
    float* __restrict__ kvc, float* __restrict__ zsum)
{
    int nh = blockIdx.x;
    int t = threadIdx.x;
    size_t base = (size_t)nh * NCH * 4096;
    for (int idx = t; idx < 4096; idx += 256) {
        float run = 0.f;
        for (int c = 0; c < NCH; ++c) {
            size_t o = base + (size_t)c*4096 + idx;
            float v = kvc[o];
            kvc[o] = run;
            run += v;
        }
    }
    if (t < 64) {
        float run = 0.f;
        size_t zb = (size_t)nh * NCH * 64;
        for (int c = 0; c < NCH; ++c) {
            size_t o = zb + (size_t)c*64 + t;
            float v = zsum[o];
            zsum[o] = run;
            run += v;
        }
    }
}

// ---------------- phase C: intra-chunk causal + inter-chunk state, normalize ----------------
__global__ __launch_bounds__(256) void attn_out(
    const u16* __restrict__ qbuf, const u16* __restrict__ kbuf,
    const u16* __restrict__ vbuf, const float* __restrict__ mask,
    const float* __restrict__ stc, const float* __restrict__ zpref,
    u16* __restrict__ att)
{
    int c = blockIdx.x, nh = blockIdx.y;
    int n = nh >> 3, h = nh & 7;
    __shared__ float sQ[64][PD], sK[64][PD], sV[64][PD], sP[64][PD];
    __shared__ float sZ[64], sInv[64];
    int t = threadIdx.x;
    for (int idx = t; idx < 4096; idx += 256) {
        int i = idx >> 6, d = idx & 63;
        int m = n*SS + c*64 + i;
        float qq = b2f(qbuf[(size_t)m*EE + h*DD + d]);
        sQ[i][d] = qq > 0.f ? qq + 1.f : expf(qq);
        float kk = b2f(kbuf[(size_t)m*EE + h*DD + d]);
        float f = kk > 0.f ? kk + 1.f : expf(kk);
        sK[i][d] = f * mask[m];
        sV[i][d] = b2f(vbuf[(size_t)m*EE + h*DD + d]);
    }
    if (t < 64) sZ[t] = zpref[((size_t)nh*NCH + c)*64 + t];
    __syncthreads();
    int tr = t >> 4, tc = t & 15;
    // P = Qf @ Kf^T
    {
        float acc[4][4] = {};
        for (int d = 0; d < 64; d += 4) {
            float4 qa[4], kb4[4];
            #pragma unroll
            for (int a=0;a<4;++a) qa[a] = *(const float4*)&sQ[(tr<<2)+a][d];
            #pragma unroll
            for (int b=0;b<4;++b) kb4[b] = *(const float4*)&sK[(tc<<2)+b][d];
            #pragma unroll
            for (int a=0;a<4;++a) {
                float qv[4] = {qa[a].x,qa[a].y,qa[a].z,qa[a].w};
                #pragma unroll
                for (int b=0;b<4;++b) {
                    acc[a][b] += qv[0]*kb4[b].x + qv[1]*kb4[b].y
                               + qv[2]*kb4[b].z + qv[3]*kb4[b].w;
                }
            }
        }
        #pragma unroll
        for (int a=0;a<4;++a)
            *(float4*)&sP[(tr<<2)+a][tc<<2] =
                make_float4(acc[a][0],acc[a][1],acc[a][2],acc[a][3]);
    }
    __syncthreads();
    // stage inter-chunk state into sK (sK no longer needed)
    {
        size_t sb = ((size_t)nh*NCH + c) * 4096;
        for (int idx = t; idx < 4096; idx += 256)
            sK[idx>>6][idx&63] = stc[sb + idx];
    }
    // denominator per row
    if (t < 64) {
        float den = 1e-6f;
        for (int j = 0; j <= t; ++j) den += sP[t][j];
        float dz = 0.f;
        for (int d = 0; d < 64; ++d) dz += sQ[t][d] * sZ[d];
        sInv[t] = 1.0f / (den + dz);
    }
    // intra-chunk causal: sum_{j<=i} P[i][j] * V[j][:]
    float acc1[4][4] = {};
    for (int j = 0; j < 64; ++j) {
        float4 vb4 = *(const float4*)&sV[j][tc<<2];
        float vv[4] = {vb4.x, vb4.y, vb4.z, vb4.w};
        #pragma unroll
        for (int a=0;a<4;++a) {
            int i = (tr<<2)+a;
            float p = (j <= i) ? sP[i][j] : 0.f;
            #pragma unroll
            for (int b=0;b<4;++b) acc1[a][b] = fmaf(p, vv[b], acc1[a][b]);
        }
    }
    __syncthreads();   // staged state + sInv ready
    // inter-chunk: Qf @ State
    for (int d = 0; d < 64; ++d) {
        float4 sv4 = *(const float4*)&sK[d][tc<<2];
        float sv[4] = {sv4.x, sv4.y, sv4.z, sv4.w};
        #pragma unroll
        for (int a=0;a<4;++a) {
            float qv = sQ[(tr<<2)+a][d];
            #pragma unroll
            for (int b=0;b<4;++b) acc1[a][b] = fmaf(qv, sv[b], acc1[a][b]);
        }
    }
    #pragma unroll
    for (int a=0;a<4;++a) {
        int i = (tr<<2)+a;
        int m = n*SS + c*64 + i;
        float inv = sInv[i];
        size_t ob = (size_t)m*EE + h*DD + (tc<<2);
        att[ob+0] = f2b(acc1[a][0]*inv);
        att[ob+1] = f2b(acc1[a][1]*inv);
        att[ob+2] = f2b(acc1[a][2]*inv);
        att[ob+3] = f2b(acc1[a][3]*inv);
    }
}

// ---------------- LayerNorm over E=512, one block per row; optional dual write ----------------
template<int DUAL>
__global__ __launch_bounds__(256) void ln_kernel(
    const float* __restrict__ in, const float* __restrict__ g,
    const float* __restrict__ b, float* __restrict__ outf, u16* __restrict__ outh)
{
    int m = blockIdx.x;
    int t = threadIdx.x;
    float v0 = in[(size_t)m*EE + t];
    float v1 = in[(size_t)m*EE + t + 256];
    float s = v0 + v1, sq = v0*v0 + v1*v1;
    for (int o = 32; o; o >>= 1) { s += __shfl_down(s, o); sq += __shfl_down(sq, o); }
    __shared__ float ws_[4], wq_[4];
    int w = t >> 6;
    if ((t & 63) == 0) { ws_[w] = s; wq_[w] = sq; }
    __syncthreads();
    if (t == 0) {
        float S=0.f, Q=0.f;
        for (int i=0;i<4;++i){S+=ws_[i];Q+=wq_[i];}
        float mean = S * (1.0f/512.0f);
        float var = Q * (1.0f/512.0f) - mean*mean;
        ws_[0] = mean; wq_[0] = rsqrtf(var + 1e-5f);
    }
    __syncthreads();
    float mean = ws_[0], inv = wq_[0];
    float o0 = (v0-mean)*inv*g[t]+b[t];
    float o1 = (v1-mean)*inv*g[t+256]+b[t+256];
    outf[(size_t)m*EE + t]       = o0;
    outf[(size_t)m*EE + t + 256] = o1;
    if (DUAL) {
        outh[(size_t)m*EE + t]       = f2b(o0);
        outh[(size_t)m*EE + t + 256] = f2b(o1);
    }
}

extern "C" void kernel_launch(void* const* d_in, const int* in_sizes, int n_in,
                              void* d_out, int out_size, void* d_ws, size_t ws_size,
                              hipStream_t stream)
{
    (void)in_sizes; (void)n_in; (void)out_size; (void)ws_size;
    const int*   seq = (const int*)d_in[0];
    const int*   dep = (const int*)d_in[1];
    const int*   pos = (const int*)d_in[2];
    const float* tok = (const float*)d_in[3];
    const float* dem = (const float*)d_in[4];
    const float* sp  = (const float*)d_in[5];
    const float* sos = (const float*)d_in[6];
    const float* Wq  = (const float*)d_in[7];
    const float* bq  = (const float*)d_in[8];
    const float* Wk  = (const float*)d_in[9];
    const float* bk  = (const float*)d_in[10];
    const float* Wv  = (const float*)d_in[11];
    const float* bv  = (const float*)d_in[12];
    const float* Wo  = (const float*)d_in[13];
    const float* bo  = (const float*)d_in[14];
    const float* g1  = (const float*)d_in[15];
    const float* b1  = (const float*)d_in[16];
    const float* W1  = (const float*)d_in[17];
    const float* bf1 = (const float*)d_in[18];
    const float* W2  = (const float*)d_in[19];
    const float* bf2 = (const float*)d_in[20];
    const float* g2  = (const float*)d_in[21];
    const float* b2  = (const float*)d_in[22];
    const float* gf  = (const float*)d_in[23];
    const float* bfn = (const float*)d_in[24];
    const float* Wh  = (const float*)d_in[25];
    float* out = (float*)d_out;

    // -------- workspace layout (fp32 region, then bf16 region) --------
    float* xf    = (float*)d_ws;                   // MM*EE
    float* yb    = xf   + (size_t)MM*EE;           // MM*EE
    float* kvc   = yb   + (size_t)MM*EE;           // NHH*NCH*4096
    float* zsum  = kvc  + (size_t)NHH*NCH*DD*DD;   // NHH*NCH*64
    float* maskb = zsum + (size_t)NHH*NCH*DD;      // MM
    u16* xh   = (u16*)(maskb + MM);                // MM*EE
    u16* qb   = xh + (size_t)MM*EE;                // union region: {qb,kb,vb,attb} / {h1}
    u16* kb   = qb + (size_t)MM*EE;
    u16* vb   = kb + (size_t)MM*EE;
    u16* attb = vb + (size_t)MM*EE;
    u16* h1   = qb;                                // overlay (4*MM*EE == MM*FFD)
    u16* wq16 = attb + (size_t)MM*EE;              // L*EE*EE each
    u16* wk16 = wq16 + (size_t)LL*EE*EE;
    u16* wv16 = wk16 + (size_t)LL*EE*EE;
    u16* wo16 = wv16 + (size_t)LL*EE*EE;
    u16* w116 = wo16 + (size_t)LL*EE*EE;           // L*FFD*EE
    u16* w216 = w116 + (size_t)LL*FFD*EE;          // L*FFD*EE

    dim3 blk(256);
    dim3 gE(EE/64,  MM/64);     // 8,32
    dim3 gQKV(EE/64, MM/64, 3); // 8,32,3 -> 768 blocks
    dim3 gF(FFD/64, MM/64);     // 32,32
    dim3 gA(NCH, NHH);

    // weight conversion (once per launch)
    f2b_kernel<<<(LL*EE*EE)/2048,  blk, 0, stream>>>(Wq, wq16);
    f2b_kernel<<<(LL*EE*EE)/2048,  blk, 0, stream>>>(Wk, wk16);
    f2b_kernel<<<(LL*EE*EE)/2048,  blk, 0, stream>>>(Wv, wv16);
    f2b_kernel<<<(LL*EE*EE)/2048,  blk, 0, stream>>>(Wo, wo16);
    f2b_kernel<<<(LL*FFD*EE)/2048, blk, 0, stream>>>(W1, w116);
    f2b_kernel<<<(LL*FFD*EE)/2048, blk, 0, stream>>>(W2, w216);

    embed_kernel<<<MM, blk, 0, stream>>>(seq, dep, pos, tok, dem, sp, sos, xf, xh, maskb);
    for (int l = 0; l < LL; ++l) {
        gemm_qkv<<<gQKV, blk, 0, stream>>>(
            xh, wq16 + (size_t)l*EE*EE, wk16 + (size_t)l*EE*EE, wv16 + (size_t)l*EE*EE,
            bq + (size_t)l*EE, bk + (size_t)l*EE, bv + (size_t)l*EE,
            qb, kb, vb, EE, EE);
        attn_kv<<<gA, blk, 0, stream>>>(kb, vb, maskb, kvc, zsum);
        attn_prefix<<<NHH, blk, 0, stream>>>(kvc, zsum);
        attn_out<<<gA, blk, 0, stream>>>(qb, kb, vb, maskb, kvc, zsum, attb);
        gemm_k<0,1><<<gE, blk, 0, stream>>>(attb, wo16 + (size_t)l*EE*EE,
            bo + (size_t)l*EE, xf, yb, nullptr, EE, EE);
        ln_kernel<1><<<MM, blk, 0, stream>>>(yb, g1 + (size_t)l*EE, b1 + (size_t)l*EE, xf, xh);
        gemm_k<1,0><<<gF, blk, 0, stream>>>(xh, w116 + (size_t)l*FFD*EE,
            bf1 + (size_t)l*FFD, nullptr, nullptr, h1, FFD, EE);
        gemm_k<0,1><<<gE, blk, 0, stream>>>(h1, w216 + (size_t)l*EE*FFD,
            bf2 + (size_t)l*EE, xf, yb, nullptr, EE, FFD);
        ln_kernel<1><<<MM, blk, 0, stream>>>(yb, g2 + (size_t)l*EE, b2 + (size_t)l*EE, xf, xh);
    }
    ln_kernel<0><<<MM, blk, 0, stream>>>(xf, gf, bfn, yb, nullptr);
    gemm_head<<<dim3(1, MM/64), blk, 0, stream>>>(yb, Wh, out, MM, VO, EE);
}

// Round 6
// 484.511 us; speedup vs baseline: 3.4887x; 1.2369x over previous
//
#include <hip/hip_runtime.h>
#include <hip/hip_bf16.h>

#define NB 2
#define SS 1024
#define EE 512
#define HH 8
#define DD 64
#define LL 4
#define FFD 2048
#define VO 17
#define MM (NB*SS)
#define CH 64
#define NCH (SS/CH)   /* 16 chunks per sequence */
#define NHH (NB*HH)   /* 16 (n,h) pairs */
#define PD 68         /* padded LDS stride (fp32 attn tiles) */

typedef __attribute__((ext_vector_type(8))) short bshort8;
typedef __attribute__((ext_vector_type(4))) float f32x4;
typedef unsigned short u16;

__device__ __forceinline__ float b2f(u16 u) {
    return __uint_as_float(((unsigned)u) << 16);
}
__device__ __forceinline__ u16 f2b(float f) {
    unsigned u = __float_as_uint(f);
    u += 0x7fffu + ((u >> 16) & 1u);          // RNE to bf16 (finite inputs)
    return (u16)(u >> 16);
}

// ---------------- fp32 -> bf16 bulk convert: ALL weights in ONE dispatch ----------------
// blocks 0..511 -> Wq, 512..1023 -> Wk, 1024..1535 -> Wv, 1536..2047 -> Wo,
// 2048..4095 -> W1, 4096..6143 -> W2.  2048 elems per block.
__global__ __launch_bounds__(256) void f2b_all(
    const float* __restrict__ Wq, const float* __restrict__ Wk,
    const float* __restrict__ Wv, const float* __restrict__ Wo,
    const float* __restrict__ W1, const float* __restrict__ W2,
    u16* __restrict__ dq, u16* __restrict__ dk, u16* __restrict__ dv,
    u16* __restrict__ do_, u16* __restrict__ d1, u16* __restrict__ d2)
{
    int b = blockIdx.x;
    const float* src; u16* dst; size_t off;
    if (b < 2048) {
        int r = b >> 9, o = b & 511;
        src = (r==0)?Wq:(r==1)?Wk:(r==2)?Wv:Wo;
        dst = (r==0)?dq:(r==1)?dk:(r==2)?dv:do_;
        off = (size_t)o * 2048;
    } else {
        int bb = b - 2048;
        int r = bb >> 11, o = bb & 2047;
        src = r ? W2 : W1;
        dst = r ? d2 : d1;
        off = (size_t)o * 2048;
    }
    size_t i = off + (size_t)threadIdx.x * 8;
    float4 v0 = *(const float4*)(src + i);
    float4 v1 = *(const float4*)(src + i + 4);
    bshort8 rr;
    rr[0]=(short)f2b(v0.x); rr[1]=(short)f2b(v0.y); rr[2]=(short)f2b(v0.z); rr[3]=(short)f2b(v0.w);
    rr[4]=(short)f2b(v1.x); rr[5]=(short)f2b(v1.y); rr[6]=(short)f2b(v1.z); rr[7]=(short)f2b(v1.w);
    *(bshort8*)(dst + i) = rr;
}

// ---------------- embeddings + shift-right + key mask (dual fp32/bf16 out) ----------------
__global__ __launch_bounds__(256) void embed_kernel(
    const int* __restrict__ seq, const int* __restrict__ dep,
    const int* __restrict__ pos, const float* __restrict__ tok,
    const float* __restrict__ dem, const float* __restrict__ sp,
    const float* __restrict__ sos, float* __restrict__ xf, u16* __restrict__ xh,
    float* __restrict__ mask)
{
    int m = blockIdx.x;
    int s = m % SS;
    int t = threadIdx.x;
    if (t == 0) mask[m] = (seq[m] != 0) ? 1.0f : 0.0f;
    if (s == 0) {
        for (int e = t; e < EE; e += 256) {
            float v = sos[e];
            xf[(size_t)m*EE+e] = v; xh[(size_t)m*EE+e] = f2b(v);
        }
    } else {
        int mp = m - 1;
        int tk = seq[mp];
        int dh = dep[mp];
        int p0 = pos[0*NB*SS+mp], p1 = pos[1*NB*SS+mp], p2 = pos[2*NB*SS+mp];
        const float* r0 = tok + (size_t)tk*EE;
        const float* r1 = dem + (size_t)dh*EE;
        const float* r2 = sp + ((size_t)0*65 + p0)*EE;
        const float* r3 = sp + ((size_t)1*65 + p1)*EE;
        const float* r4 = sp + ((size_t)2*65 + p2)*EE;
        for (int e = t; e < EE; e += 256) {
            float v = r0[e] + r1[e] + r2[e] + r3[e] + r4[e];
            xf[(size_t)m*EE+e] = v; xh[(size_t)m*EE+e] = f2b(v);
        }
    }
}

// ---------------- bf16 MFMA GEMM body ----------------
// A: [*,Kstride] bf16 (pre-offset to tile k0), W likewise. Loop length KL.
// MODE 0: Ch[row*Nn+col] = act(acc + bias)   (bf16 out)
// MODE 2: Cf[row*Nn+col] = acc               (fp32 partial, no bias/act)
// 64x64 tile, BK=64 double-buffered LDS, one barrier per K-tile.
template<int ACT, int MODE>
__device__ __forceinline__ void gemm_body(
    const u16* __restrict__ A, const u16* __restrict__ W,
    int Kstride, int KL, const float* __restrict__ bias,
    u16* __restrict__ Ch, float* __restrict__ Cf,
    int m0, int n0, int Nn)
{
    __shared__ u16 sA[2][64][72];   // 144B row stride: 16B-aligned, ~2-way banks
    __shared__ u16 sB[2][64][72];
    int t = threadIdx.x;
    int lane = t & 63, w = t >> 6, wr = w >> 1, wc = w & 1;
    int l15 = lane & 15, lk = (lane >> 4) << 3;
    int sr = t >> 2, sc = (t & 3) << 4;          // 4 threads/row, 16 bf16 each
    const u16* Ap = A + (size_t)(m0 + sr) * Kstride + sc;
    const u16* Wp = W + (size_t)(n0 + sr) * Kstride + sc;
    int T = KL >> 6;
    bshort8 ra0 = *(const bshort8*)(Ap);
    bshort8 ra1 = *(const bshort8*)(Ap + 8);
    bshort8 rb0 = *(const bshort8*)(Wp);
    bshort8 rb1 = *(const bshort8*)(Wp + 8);
    *(bshort8*)&sA[0][sr][sc]   = ra0;  *(bshort8*)&sA[0][sr][sc+8] = ra1;
    *(bshort8*)&sB[0][sr][sc]   = rb0;  *(bshort8*)&sB[0][sr][sc+8] = rb1;
    __syncthreads();
    f32x4 acc[2][2] = {};
    for (int tt = 0; tt < T; ++tt) {
        int cur = tt & 1;
        bool more = (tt + 1 < T);
        if (more) {                               // issue next-tile loads early
            int kk = (tt + 1) << 6;
            ra0 = *(const bshort8*)(Ap + kk);
            ra1 = *(const bshort8*)(Ap + kk + 8);
            rb0 = *(const bshort8*)(Wp + kk);
            rb1 = *(const bshort8*)(Wp + kk + 8);
        }
        #pragma unroll
        for (int ks = 0; ks < 2; ++ks) {
            bshort8 af[2], bfr[2];
            #pragma unroll
            for (int mi=0;mi<2;++mi)
                af[mi] = *(const bshort8*)&sA[cur][wr*32+mi*16+l15][(ks<<5)+lk];
            #pragma unroll
            for (int ni=0;ni<2;++ni)
                bfr[ni] = *(const bshort8*)&sB[cur][wc*32+ni*16+l15][(ks<<5)+lk];
            #pragma unroll
            for (int mi=0;mi<2;++mi)
                #pragma unroll
                for (int ni=0;ni<2;++ni)
                    acc[mi][ni] = __builtin_amdgcn_mfma_f32_16x16x32_bf16(
                        af[mi], bfr[ni], acc[mi][ni], 0, 0, 0);
        }
        if (more) {
            int nxt = cur ^ 1;
            *(bshort8*)&sA[nxt][sr][sc]   = ra0;  *(bshort8*)&sA[nxt][sr][sc+8] = ra1;
            *(bshort8*)&sB[nxt][sr][sc]   = rb0;  *(bshort8*)&sB[nxt][sr][sc+8] = rb1;
            __syncthreads();                      // one barrier per K-tile
        }
    }
    int r0 = (lane >> 4) << 2;
    #pragma unroll
    for (int mi=0;mi<2;++mi) {
        #pragma unroll
        for (int ni=0;ni<2;++ni) {
            int col = n0 + wc*32 + ni*16 + l15;
            float bs = (MODE == 0) ? bias[col] : 0.f;
            #pragma unroll
            for (int r=0;r<4;++r) {
                int row = m0 + wr*32 + mi*16 + r0 + r;
                float v = acc[mi][ni][r] + bs;
                if (ACT == 1) v = 0.5f * v * (1.0f + erff(v * 0.70710678118654752f));
                if (MODE == 0) Ch[(size_t)row*Nn + col] = f2b(v);
                else           Cf[(size_t)row*Nn + col] = v;
            }
        }
    }
}

template<int ACT>
__global__ __launch_bounds__(256) void gemm_k(
    const u16* __restrict__ A, const u16* __restrict__ W,
    const float* __restrict__ bias, u16* __restrict__ Ch, int Nn, int K)
{
    gemm_body<ACT,0>(A, W, K, K, bias, Ch, nullptr, blockIdx.y*64, blockIdx.x*64, Nn);
}

// split-K partial GEMM: blockIdx.z selects K-half, writes fp32 partial buffer z
__global__ __launch_bounds__(256) void gemm_part(
    const u16* __restrict__ A, const u16* __restrict__ W,
    float* __restrict__ P, int Nn, int Kfull, int KL)
{
    int z = blockIdx.z;
    gemm_body<0,2>(A + (size_t)z*KL, W + (size_t)z*KL, Kfull, KL, nullptr,
                   nullptr, P + (size_t)z*MM*Nn, blockIdx.y*64, blockIdx.x*64, Nn);
}

// fused Q,K,V: blockIdx.z selects projection -> 3x grid, 3 blocks/CU
__global__ __launch_bounds__(256) void gemm_qkv(
    const u16* __restrict__ A,
    const u16* __restrict__ Wq, const u16* __restrict__ Wk, const u16* __restrict__ Wv,
    const float* __restrict__ bq, const float* __restrict__ bk, const float* __restrict__ bv,
    u16* __restrict__ qb, u16* __restrict__ kb, u16* __restrict__ vb, int Nn, int K)
{
    int z = blockIdx.z;
    const u16* W = (z==0) ? Wq : (z==1 ? Wk : Wv);
    const float* bias = (z==0) ? bq : (z==1 ? bk : bv);
    u16* Ch = (z==0) ? qb : (z==1 ? kb : vb);
    gemm_body<0,0>(A, W, K, K, bias, Ch, nullptr, blockIdx.y*64, blockIdx.x*64, Nn);
}

// ---------------- fp32 GEMM (head only, Nn=17): C = A @ W^T ----------------
__global__ __launch_bounds__(256) void gemm_head(
    const float* __restrict__ A, const float* __restrict__ W,
    float* __restrict__ C, int M, int Nn, int K)
{
    __shared__ float sA[16][64];
    __shared__ float sB[16][64];
    int t = threadIdx.x;
    int tx = t & 15, ty = t >> 4;
    int m0 = blockIdx.y * 64, n0 = blockIdx.x * 64;
    int lr = t >> 2;
    int lc = (t & 3) << 2;
    const float* Ap = A + (size_t)(m0+lr)*K + lc;
    const float* Wp = (n0+lr < Nn) ? (W + (size_t)(n0+lr)*K + lc) : nullptr;
    float acc[4][4] = {};
    for (int kk = 0; kk < K; kk += 16) {
        float4 a4 = *(const float4*)(Ap + kk);
        float4 b4 = Wp ? *(const float4*)(Wp + kk) : make_float4(0.f,0.f,0.f,0.f);
        __syncthreads();
        sA[lc+0][lr]=a4.x; sA[lc+1][lr]=a4.y; sA[lc+2][lr]=a4.z; sA[lc+3][lr]=a4.w;
        sB[lc+0][lr]=b4.x; sB[lc+1][lr]=b4.y; sB[lc+2][lr]=b4.z; sB[lc+3][lr]=b4.w;
        __syncthreads();
        #pragma unroll
        for (int k = 0; k < 16; ++k) {
            float4 av = *(const float4*)&sA[k][ty<<2];
            float4 bv = *(const float4*)&sB[k][tx<<2];
            float aa[4] = {av.x, av.y, av.z, av.w};
            float bb[4] = {bv.x, bv.y, bv.z, bv.w};
            #pragma unroll
            for (int i=0;i<4;++i)
                #pragma unroll
                for (int j=0;j<4;++j)
                    acc[i][j] = fmaf(aa[i], bb[j], acc[i][j]);
        }
    }
    #pragma unroll
    for (int i=0;i<4;++i) {
        int mr = m0 + (ty<<2) + i;
        #pragma unroll
        for (int j=0;j<4;++j) {
            int nc = n0 + (tx<<2) + j;
            if (nc < Nn) C[(size_t)mr*Nn + nc] = acc[i][j];
        }
    }
}

// ---------------- chunked linear attention, phase A: per-chunk KV = Kf^T V, zsum ----------------
__global__ __launch_bounds__(256) void attn_kv(
    const u16* __restrict__ kbuf, const u16* __restrict__ vbuf,
    const float* __restrict__ mask, float* __restrict__ kvc, float* __restrict__ zsum)
{
    int c = blockIdx.x, nh = blockIdx.y;
    int n = nh >> 3, h = nh & 7;
    __shared__ float sK[64][PD];
    __shared__ float sV[64][PD];
    int t = threadIdx.x;
    for (int idx = t; idx < 4096; idx += 256) {
        int i = idx >> 6, d = idx & 63;
        int m = n*SS + c*64 + i;
        float kk = b2f(kbuf[(size_t)m*EE + h*DD + d]);
        float f = kk > 0.f ? kk + 1.f : expf(kk);
        sK[i][d] = f * mask[m];
        sV[i][d] = b2f(vbuf[(size_t)m*EE + h*DD + d]);
    }
    __syncthreads();
    int tr = t >> 4, tc = t & 15;
    float acc[4][4] = {};
    for (int i = 0; i < 64; ++i) {
        float4 kd = *(const float4*)&sK[i][tr<<2];
        float4 vm = *(const float4*)&sV[i][tc<<2];
        float ka[4]={kd.x,kd.y,kd.z,kd.w}, vv[4]={vm.x,vm.y,vm.z,vm.w};
        #pragma unroll
        for (int a=0;a<4;++a)
            #pragma unroll
            for (int b=0;b<4;++b)
                acc[a][b] = fmaf(ka[a], vv[b], acc[a][b]);
    }
    size_t base = ((size_t)nh*NCH + c) * 4096;
    #pragma unroll
    for (int a=0;a<4;++a)
        *(float4*)&kvc[base + (size_t)((tr<<2)+a)*64 + (tc<<2)] =
            make_float4(acc[a][0],acc[a][1],acc[a][2],acc[a][3]);
    if (t < 64) {
        float z = 0.f;
        for (int i = 0; i < 64; ++i) z += sK[i][t];
        zsum[((size_t)nh*NCH + c)*64 + t] = z;
    }
}

// ---------------- phase B: IN-PLACE exclusive prefix over chunks, PARALLEL ----------------
// grid (16 slices, NHH). Each thread owns one state element; 16 chunk loads are
// independent (pipelined), prefix in registers.
__global__ __launch_bounds__(256) void attn_prefix(
    float* __restrict__ kvc, float* __restrict__ zsum)
{
    int s = blockIdx.x, nh = blockIdx.y;
    int t = threadIdx.x;
    int idx = s * 256 + t;
    size_t base = (size_t)nh * NCH * 4096 + idx;
    float v[NCH];
    #pragma unroll
    for (int c = 0; c < NCH; ++c) v[c] = kvc[base + (size_t)c*4096];
    float run = 0.f;
    #pragma unroll
    for (int c = 0; c < NCH; ++c) {
        kvc[base + (size_t)c*4096] = run;
        run += v[c];
    }
    if (s == 0 && t < 64) {
        size_t zb = (size_t)nh * NCH * 64 + t;
        float zv[NCH];
        #pragma unroll
        for (int c = 0; c < NCH; ++c) zv[c] = zsum[zb + (size_t)c*64];
        float zr = 0.f;
        #pragma unroll
        for (int c = 0; c < NCH; ++c) {
            zsum[zb + (size_t)c*64] = zr;
            zr += zv[c];
        }
    }
}

// ---------------- phase C: intra-chunk causal + inter-chunk state, normalize ----------------
__global__ __launch_bounds__(256) void attn_out(
    const u16* __restrict__ qbuf, const u16* __restrict__ kbuf,
    const u16* __restrict__ vbuf, const float* __restrict__ mask,
    const float* __restrict__ stc, const float* __restrict__ zpref,
    u16* __restrict__ att)
{
    int c = blockIdx.x, nh = blockIdx.y;
    int n = nh >> 3, h = nh & 7;
    __shared__ float sQ[64][PD], sK[64][PD], sV[64][PD], sP[64][PD];
    __shared__ float sZ[64], sInv[64];
    __shared__ float sDen[64][4];
    int t = threadIdx.x;
    for (int idx = t; idx < 4096; idx += 256) {
        int i = idx >> 6, d = idx & 63;
        int m = n*SS + c*64 + i;
        float qq = b2f(qbuf[(size_t)m*EE + h*DD + d]);
        sQ[i][d] = qq > 0.f ? qq + 1.f : expf(qq);
        float kk = b2f(kbuf[(size_t)m*EE + h*DD + d]);
        float f = kk > 0.f ? kk + 1.f : expf(kk);
        sK[i][d] = f * mask[m];
        sV[i][d] = b2f(vbuf[(size_t)m*EE + h*DD + d]);
    }
    if (t < 64) sZ[t] = zpref[((size_t)nh*NCH + c)*64 + t];
    __syncthreads();
    int tr = t >> 4, tc = t & 15;
    // P = Qf @ Kf^T
    {
        float acc[4][4] = {};
        for (int d = 0; d < 64; d += 4) {
            float4 qa[4], kb4[4];
            #pragma unroll
            for (int a=0;a<4;++a) qa[a] = *(const float4*)&sQ[(tr<<2)+a][d];
            #pragma unroll
            for (int b=0;b<4;++b) kb4[b] = *(const float4*)&sK[(tc<<2)+b][d];
            #pragma unroll
            for (int a=0;a<4;++a) {
                float qv[4] = {qa[a].x,qa[a].y,qa[a].z,qa[a].w};
                #pragma unroll
                for (int b=0;b<4;++b) {
                    acc[a][b] += qv[0]*kb4[b].x + qv[1]*kb4[b].y
                               + qv[2]*kb4[b].z + qv[3]*kb4[b].w;
                }
            }
        }
        #pragma unroll
        for (int a=0;a<4;++a)
            *(float4*)&sP[(tr<<2)+a][tc<<2] =
                make_float4(acc[a][0],acc[a][1],acc[a][2],acc[a][3]);
    }
    __syncthreads();
    // stage inter-chunk state into sK (sK no longer needed)
    {
        size_t sb = ((size_t)nh*NCH + c) * 4096;
        for (int idx = t; idx < 4096; idx += 256)
            sK[idx>>6][idx&63] = stc[sb + idx];
    }
    // parallel denominator partials: 4 threads per row (quarters of j / d)
    {
        int rr = t & 63, qq = t >> 6;
        int j0 = qq << 4;
        float part = 0.f;
        #pragma unroll
        for (int j = 0; j < 16; ++j) {
            int jj = j0 + j;
            part += (jj <= rr) ? sP[rr][jj] : 0.f;
        }
        float dzp = 0.f;
        #pragma unroll
        for (int d = 0; d < 16; ++d) {
            int dd = j0 + d;
            dzp += sQ[rr][dd] * sZ[dd];
        }
        sDen[rr][qq] = part + dzp;
    }
    // intra-chunk causal: sum_{j<=i} P[i][j] * V[j][:]
    float acc1[4][4] = {};
    for (int j = 0; j < 64; ++j) {
        float4 vb4 = *(const float4*)&sV[j][tc<<2];
        float vv[4] = {vb4.x, vb4.y, vb4.z, vb4.w};
        #pragma unroll
        for (int a=0;a<4;++a) {
            int i = (tr<<2)+a;
            float p = (j <= i) ? sP[i][j] : 0.f;
            #pragma unroll
            for (int b=0;b<4;++b) acc1[a][b] = fmaf(p, vv[b], acc1[a][b]);
        }
    }
    __syncthreads();   // staged state + sDen ready
    if (t < 64)
        sInv[t] = 1.0f / (1e-6f + sDen[t][0] + sDen[t][1] + sDen[t][2] + sDen[t][3]);
    // inter-chunk: Qf @ State
    for (int d = 0; d < 64; ++d) {
        float4 sv4 = *(const float4*)&sK[d][tc<<2];
        float sv[4] = {sv4.x, sv4.y, sv4.z, sv4.w};
        #pragma unroll
        for (int a=0;a<4;++a) {
            float qv = sQ[(tr<<2)+a][d];
            #pragma unroll
            for (int b=0;b<4;++b) acc1[a][b] = fmaf(qv, sv[b], acc1[a][b]);
        }
    }
    __syncthreads();   // sInv visible to all
    #pragma unroll
    for (int a=0;a<4;++a) {
        int i = (tr<<2)+a;
        int m = n*SS + c*64 + i;
        float inv = sInv[i];
        size_t ob = (size_t)m*EE + h*DD + (tc<<2);
        att[ob+0] = f2b(acc1[a][0]*inv);
        att[ob+1] = f2b(acc1[a][1]*inv);
        att[ob+2] = f2b(acc1[a][2]*inv);
        att[ob+3] = f2b(acc1[a][3]*inv);
    }
}

// ---------------- LayerNorm over E=512, one block per row ----------------
// plain variant (final LN): in = single fp32 buffer
__global__ __launch_bounds__(256) void ln_kernel(
    const float* __restrict__ in, const float* __restrict__ g,
    const float* __restrict__ b, float* __restrict__ outf)
{
    int m = blockIdx.x;
    int t = threadIdx.x;
    float v0 = in[(size_t)m*EE + t];
    float v1 = in[(size_t)m*EE + t + 256];
    float s = v0 + v1, sq = v0*v0 + v1*v1;
    for (int o = 32; o; o >>= 1) { s += __shfl_down(s, o); sq += __shfl_down(sq, o); }
    __shared__ float ws_[4], wq_[4];
    int w = t >> 6;
    if ((t & 63) == 0) { ws_[w] = s; wq_[w] = sq; }
    __syncthreads();
    if (t == 0) {
        float S=0.f, Q=0.f;
        for (int i=0;i<4;++i){S+=ws_[i];Q+=wq_[i];}
        float mean = S * (1.0f/512.0f);
        float var = Q * (1.0f/512.0f) - mean*mean;
        ws_[0] = mean; wq_[0] = rsqrtf(var + 1e-5f);
    }
    __syncthreads();
    float mean = ws_[0], inv = wq_[0];
    outf[(size_t)m*EE + t]       = (v0-mean)*inv*g[t]+b[t];
    outf[(size_t)m*EE + t + 256] = (v1-mean)*inv*g[t+256]+b[t+256];
}

// fused variant: in = p0 + p1 + bias + resid; dual fp32/bf16 out
__global__ __launch_bounds__(256) void ln_fuse2(
    const float* __restrict__ p0, const float* __restrict__ p1,
    const float* __restrict__ bias, const float* __restrict__ resid,
    const float* __restrict__ g, const float* __restrict__ b,
    float* __restrict__ outf, u16* __restrict__ outh)
{
    int m = blockIdx.x;
    int t = threadIdx.x;
    size_t i0 = (size_t)m*EE + t, i1 = i0 + 256;
    float v0 = p0[i0] + p1[i0] + bias[t]     + resid[i0];
    float v1 = p0[i1] + p1[i1] + bias[t+256] + resid[i1];
    float s = v0 + v1, sq = v0*v0 + v1*v1;
    for (int o = 32; o; o >>= 1) { s += __shfl_down(s, o); sq += __shfl_down(sq, o); }
    __shared__ float ws_[4], wq_[4];
    int w = t >> 6;
    if ((t & 63) == 0) { ws_[w] = s; wq_[w] = sq; }
    __syncthreads();
    if (t == 0) {
        float S=0.f, Q=0.f;
        for (int i=0;i<4;++i){S+=ws_[i];Q+=wq_[i];}
        float mean = S * (1.0f/512.0f);
        float var = Q * (1.0f/512.0f) - mean*mean;
        ws_[0] = mean; wq_[0] = rsqrtf(var + 1e-5f);
    }
    __syncthreads();
    float mean = ws_[0], inv = wq_[0];
    float o0 = (v0-mean)*inv*g[t]+b[t];
    float o1 = (v1-mean)*inv*g[t+256]+b[t+256];
    outf[i0] = o0;  outf[i1] = o1;
    outh[i0] = f2b(o0);  outh[i1] = f2b(o1);
}

extern "C" void kernel_launch(void* const* d_in, const int* in_sizes, int n_in,
                              void* d_out, int out_size, void* d_ws, size_t ws_size,
                              hipStream_t stream)
{
    (void)in_sizes; (void)n_in; (void)out_size; (void)ws_size;
    const int*   seq = (const int*)d_in[0];
    const int*   dep = (const int*)d_in[1];
    const int*   pos = (const int*)d_in[2];
    const float* tok = (const float*)d_in[3];
    const float* dem = (const float*)d_in[4];
    const float* sp  = (const float*)d_in[5];
    const float* sos = (const float*)d_in[6];
    const float* Wq  = (const float*)d_in[7];
    const float* bq  = (const float*)d_in[8];
    const float* Wk  = (const float*)d_in[9];
    const float* bk  = (const float*)d_in[10];
    const float* Wv  = (const float*)d_in[11];
    const float* bv  = (const float*)d_in[12];
    const float* Wo  = (const float*)d_in[13];
    const float* bo  = (const float*)d_in[14];
    const float* g1  = (const float*)d_in[15];
    const float* b1  = (const float*)d_in[16];
    const float* W1  = (const float*)d_in[17];
    const float* bf1 = (const float*)d_in[18];
    const float* W2  = (const float*)d_in[19];
    const float* bf2 = (const float*)d_in[20];
    const float* g2  = (const float*)d_in[21];
    const float* b2  = (const float*)d_in[22];
    const float* gf  = (const float*)d_in[23];
    const float* bfn = (const float*)d_in[24];
    const float* Wh  = (const float*)d_in[25];
    float* out = (float*)d_out;

    // -------- workspace layout --------
    float* xf    = (float*)d_ws;                   // MM*EE
    float* yb    = xf   + (size_t)MM*EE;           // MM*EE (final-LN out)
    float* kvc   = yb   + (size_t)MM*EE;           // NHH*NCH*4096
    float* zsum  = kvc  + (size_t)NHH*NCH*DD*DD;   // NHH*NCH*64
    float* maskb = zsum + (size_t)NHH*NCH*DD;      // MM
    float* part  = maskb + MM;                     // 2 * MM*EE fp32 split-K partials
    u16* xh   = (u16*)(part + (size_t)2*MM*EE);    // MM*EE
    u16* qb   = xh + (size_t)MM*EE;                // union region: {qb,kb,vb,attb} / {h1}
    u16* kb   = qb + (size_t)MM*EE;
    u16* vb   = kb + (size_t)MM*EE;
    u16* attb = vb + (size_t)MM*EE;
    u16* h1   = qb;                                // overlay (4*MM*EE == MM*FFD)
    u16* wq16 = attb + (size_t)MM*EE;              // L*EE*EE each
    u16* wk16 = wq16 + (size_t)LL*EE*EE;
    u16* wv16 = wk16 + (size_t)LL*EE*EE;
    u16* wo16 = wv16 + (size_t)LL*EE*EE;
    u16* w116 = wo16 + (size_t)LL*EE*EE;           // L*FFD*EE
    u16* w216 = w116 + (size_t)LL*FFD*EE;          // L*FFD*EE

    dim3 blk(256);
    dim3 gQKV(EE/64, MM/64, 3);  // 8,32,3 -> 768 blocks
    dim3 gF(FFD/64, MM/64);      // 32,32 -> 1024
    dim3 gS(EE/64,  MM/64, 2);   // 8,32,2 -> 512 (split-K)
    dim3 gA(NCH, NHH);           // 16,16
    dim3 gP(NCH, NHH);           // 16 slices, 16 nh

    f2b_all<<<6144, blk, 0, stream>>>(Wq, Wk, Wv, Wo, W1, W2,
                                      wq16, wk16, wv16, wo16, w116, w216);
    embed_kernel<<<MM, blk, 0, stream>>>(seq, dep, pos, tok, dem, sp, sos, xf, xh, maskb);
    for (int l = 0; l < LL; ++l) {
        gemm_qkv<<<gQKV, blk, 0, stream>>>(
            xh, wq16 + (size_t)l*EE*EE, wk16 + (size_t)l*EE*EE, wv16 + (size_t)l*EE*EE,
            bq + (size_t)l*EE, bk + (size_t)l*EE, bv + (size_t)l*EE,
            qb, kb, vb, EE, EE);
        attn_kv<<<gA, blk, 0, stream>>>(kb, vb, maskb, kvc, zsum);
        attn_prefix<<<gP, blk, 0, stream>>>(kvc, zsum);
        attn_out<<<gA, blk, 0, stream>>>(qb, kb, vb, maskb, kvc, zsum, attb);
        gemm_part<<<gS, blk, 0, stream>>>(attb, wo16 + (size_t)l*EE*EE, part, EE, EE, EE/2);
        ln_fuse2<<<MM, blk, 0, stream>>>(part, part + (size_t)MM*EE, bo + (size_t)l*EE,
                                         xf, g1 + (size_t)l*EE, b1 + (size_t)l*EE, xf, xh);
        gemm_k<1><<<gF, blk, 0, stream>>>(xh, w116 + (size_t)l*FFD*EE,
                                          bf1 + (size_t)l*FFD, h1, FFD, EE);
        gemm_part<<<gS, blk, 0, stream>>>(h1, w216 + (size_t)l*EE*FFD, part, EE, FFD, FFD/2);
        ln_fuse2<<<MM, blk, 0, stream>>>(part, part + (size_t)MM*EE, bf2 + (size_t)l*EE,
                                         xf, g2 + (size_t)l*EE, b2 + (size_t)l*EE, xf, xh);
    }
    ln_kernel<<<MM, blk, 0, stream>>>(xf, gf, bfn, yb);
    gemm_head<<<dim3(1, MM/64), blk, 0, stream>>>(yb, Wh, out, MM, VO, EE);
}